// Round 2
// baseline (508.167 us; speedup 1.0000x reference)
//
#include <hip/hip_runtime.h>

#define B_SZ 256
#define T_SZ 2048
#define D_SZ 64
#define BLOCK_THREADS 256
#define WAVES_PER_BLOCK 4
#define ROWS_PER_BLOCK 256                                // rows of one b per block
#define ROWS_PER_WAVE (ROWS_PER_BLOCK / WAVES_PER_BLOCK)  // 64
#define ROW_GROUP 4

__device__ __forceinline__ float fast_tanh(float s) {
    // 1 - 2/(1+exp(2s)); saturates correctly at +-inf
    return 1.0f - 2.0f * __builtin_amdgcn_rcpf(1.0f + __expf(2.0f * s));
}

// Lane l owns column d=l. Wave processes rows of one b sequentially.
// Kernel 1: S[b][d] = sum_t exp(tanh(x[b,t,:]@W[:,d] + bias[t,d]))
__global__ __launch_bounds__(BLOCK_THREADS, 2) void tca_colsum(
        const float* __restrict__ x, const float* __restrict__ W,
        const float* __restrict__ bias, float* __restrict__ S) {
    const int wave = threadIdx.x >> 6;
    const int lane = threadIdx.x & 63;
    const int bb = blockIdx.x / (T_SZ / ROWS_PER_BLOCK);
    const int tbase = (blockIdx.x % (T_SZ / ROWS_PER_BLOCK)) * ROWS_PER_BLOCK
                    + wave * ROWS_PER_WAVE;

    // W column `lane` into registers (64 VGPRs), coalesced loads
    float Wc[D_SZ];
#pragma unroll
    for (int k = 0; k < D_SZ; ++k) Wc[k] = W[k * D_SZ + lane];

    const float* xb = x + ((size_t)bb * T_SZ + tbase) * D_SZ;
    const float* bp = bias + (size_t)tbase * D_SZ;

    float csum = 0.0f;
    for (int rg = 0; rg < ROWS_PER_WAVE; rg += ROW_GROUP) {
        float s[ROW_GROUP][4];
#pragma unroll
        for (int r = 0; r < ROW_GROUP; ++r)
#pragma unroll
            for (int j = 0; j < 4; ++j) s[r][j] = 0.0f;

#pragma unroll
        for (int kk = 0; kk < D_SZ / 4; ++kk) {
#pragma unroll
            for (int r = 0; r < ROW_GROUP; ++r) {
                const float4 xv = *(const float4*)(xb + (rg + r) * D_SZ + kk * 4);
                s[r][0] += xv.x * Wc[kk * 4 + 0];
                s[r][1] += xv.y * Wc[kk * 4 + 1];
                s[r][2] += xv.z * Wc[kk * 4 + 2];
                s[r][3] += xv.w * Wc[kk * 4 + 3];
            }
        }
#pragma unroll
        for (int r = 0; r < ROW_GROUP; ++r) {
            float sv = (s[r][0] + s[r][1]) + (s[r][2] + s[r][3]);
            sv += bp[(rg + r) * D_SZ + lane];  // coalesced
            csum += __expf(fast_tanh(sv));
        }
    }
    atomicAdd(&S[bb * D_SZ + lane], csum);
}

// Kernel 2: out[b,t,d] = x[b,t,d] * exp(tanh(...)) / S[b,d]
__global__ __launch_bounds__(BLOCK_THREADS, 2) void tca_out(
        const float* __restrict__ x, const float* __restrict__ W,
        const float* __restrict__ bias, const float* __restrict__ S,
        float* __restrict__ out) {
    const int wave = threadIdx.x >> 6;
    const int lane = threadIdx.x & 63;
    const int bb = blockIdx.x / (T_SZ / ROWS_PER_BLOCK);
    const int tbase = (blockIdx.x % (T_SZ / ROWS_PER_BLOCK)) * ROWS_PER_BLOCK
                    + wave * ROWS_PER_WAVE;

    float Wc[D_SZ];
#pragma unroll
    for (int k = 0; k < D_SZ; ++k) Wc[k] = W[k * D_SZ + lane];

    const float rcpS = __builtin_amdgcn_rcpf(S[bb * D_SZ + lane]);

    const float* xb = x + ((size_t)bb * T_SZ + tbase) * D_SZ;
    const float* bp = bias + (size_t)tbase * D_SZ;
    float* ob = out + ((size_t)bb * T_SZ + tbase) * D_SZ;

    for (int rg = 0; rg < ROWS_PER_WAVE; rg += ROW_GROUP) {
        float s[ROW_GROUP][4];
#pragma unroll
        for (int r = 0; r < ROW_GROUP; ++r)
#pragma unroll
            for (int j = 0; j < 4; ++j) s[r][j] = 0.0f;

#pragma unroll
        for (int kk = 0; kk < D_SZ / 4; ++kk) {
#pragma unroll
            for (int r = 0; r < ROW_GROUP; ++r) {
                const float4 xv = *(const float4*)(xb + (rg + r) * D_SZ + kk * 4);
                s[r][0] += xv.x * Wc[kk * 4 + 0];
                s[r][1] += xv.y * Wc[kk * 4 + 1];
                s[r][2] += xv.z * Wc[kk * 4 + 2];
                s[r][3] += xv.w * Wc[kk * 4 + 3];
            }
        }
#pragma unroll
        for (int r = 0; r < ROW_GROUP; ++r) {
            float sv = (s[r][0] + s[r][1]) + (s[r][2] + s[r][3]);
            sv += bp[(rg + r) * D_SZ + lane];
            const float p = __expf(fast_tanh(sv));
            const float xl = xb[(rg + r) * D_SZ + lane];  // coalesced per-lane element
            ob[(rg + r) * D_SZ + lane] = xl * p * rcpS;   // coalesced store
        }
    }
}

extern "C" void kernel_launch(void* const* d_in, const int* in_sizes, int n_in,
                              void* d_out, int out_size, void* d_ws, size_t ws_size,
                              hipStream_t stream) {
    const float* x = (const float*)d_in[0];
    const float* W = (const float*)d_in[1];
    const float* bias = (const float*)d_in[2];
    float* out = (float*)d_out;
    float* S = (float*)d_ws;  // B*D floats = 64 KB

    hipMemsetAsync(S, 0, B_SZ * D_SZ * sizeof(float), stream);

    const dim3 grid(B_SZ * (T_SZ / ROWS_PER_BLOCK));
    const dim3 block(BLOCK_THREADS);
    tca_colsum<<<grid, block, 0, stream>>>(x, W, bias, S);
    tca_out<<<grid, block, 0, stream>>>(x, W, bias, S, out);
}

// Round 3
// 206.485 us; speedup vs baseline: 2.4610x; 2.4610x over previous
//
#include <hip/hip_runtime.h>

#define B_SZ 256
#define T_SZ 2048
#define D_SZ 64
#define TILE_T 64
#define NT (T_SZ / TILE_T)   // 32 t-chunks
#define WAVES 4
#define BIAS_P 65            // padded bias tile row (floats)
#define SLAB_P 17            // padded slab row (floats)

__device__ __forceinline__ float fast_tanh(float s) {
    // 1 - 2/(1+exp(2s)); saturates correctly at +-inf
    return 1.0f - 2.0f * __builtin_amdgcn_rcpf(1.0f + __expf(2.0f * s));
}

// Transpose W (64x64) into ws so that column d is contiguous: Wt[d][k] = W[k][d]
__global__ __launch_bounds__(256) void tca_prep(const float* __restrict__ W,
                                                float* __restrict__ Wt) {
    const int i = threadIdx.x;
#pragma unroll
    for (int q = 0; q < 16; ++q) {
        const int idx = i + q * 256;      // 0..4095
        const int d = idx >> 6, k = idx & 63;
        Wt[d * D_SZ + k] = W[k * D_SZ + d];
    }
}

// PASS 0: S[b][d] += sum over this tile's rows of exp(tanh(x@W + bias))
// PASS 1: out[b,t,d] = x[b,t,d] * exp(tanh(x@W + bias)) * rcp(S[b,d])
template <int PASS>
__global__ __launch_bounds__(256, 3) void tca_main(
        const float* __restrict__ x, const float* __restrict__ Wt,
        const float* __restrict__ bias, float* __restrict__ S,
        float* __restrict__ out) {
    __shared__ float lds_bias[TILE_T * BIAS_P];
    __shared__ float slab[WAVES][TILE_T * SLAB_P];

    const int wave = threadIdx.x >> 6;
    const int lane = threadIdx.x & 63;
    const int tchunk = blockIdx.x % NT;
    const int bgroup = blockIdx.x / NT;
    const int b = bgroup * WAVES + wave;
    const int t0 = tchunk * TILE_T;

    // Stage bias tile [64 rows][64 cols] -> lds_bias[r*65 + k] (coalesced reads)
#pragma unroll
    for (int q = 0; q < 4; ++q) {
        const int idx = threadIdx.x + q * 256;        // 0..1023 float4-quads
        const int r = idx >> 4;
        const int c4 = (idx & 15) * 4;
        const float4 bq = *(const float4*)(bias + (size_t)(t0 + r) * D_SZ + c4);
        lds_bias[r * BIAS_P + c4 + 0] = bq.x;
        lds_bias[r * BIAS_P + c4 + 1] = bq.y;
        lds_bias[r * BIAS_P + c4 + 2] = bq.z;
        lds_bias[r * BIAS_P + c4 + 3] = bq.w;
    }
    __syncthreads();

    // This lane's x row (64 floats) into registers — statically indexed only.
    const float* xrow = x + ((size_t)b * T_SZ + t0 + lane) * D_SZ;
    float4 xr[16];
#pragma unroll
    for (int k = 0; k < 16; ++k) xr[k] = ((const float4*)xrow)[k];

    float mycs = 0.0f;      // PASS 0: this tile's column sum for d == lane
    float rcpS_v = 0.0f;    // PASS 1: rcp(S[b][lane]) held at lane = d
    if (PASS == 1) rcpS_v = __builtin_amdgcn_rcpf(S[b * D_SZ + lane]);

    float* myslab = slab[wave];   // per-wave private: no __syncthreads needed

#pragma unroll
    for (int s = 0; s < 4; ++s) {
#pragma unroll 2
        for (int dd = 0; dd < 16; ++dd) {
            const int d = s * 16 + dd;
            const float4* wq = (const float4*)(Wt + d * D_SZ);  // wave-uniform, hot
            float a0 = 0.f, a1 = 0.f, a2 = 0.f, a3 = 0.f;
#pragma unroll
            for (int k = 0; k < 16; ++k) {
                const float4 w4 = wq[k];
                a0 += xr[k].x * w4.x;
                a1 += xr[k].y * w4.y;
                a2 += xr[k].z * w4.z;
                a3 += xr[k].w * w4.w;
            }
            float sv = (a0 + a1) + (a2 + a3);
            sv += lds_bias[lane * BIAS_P + d];        // bank = (lane+d)%32: free
            const float p = __expf(fast_tanh(sv));
            if (PASS == 0) {
                myslab[lane * SLAB_P + dd] = p;
            } else {
                const float rs = __int_as_float(
                    __builtin_amdgcn_readlane(__float_as_int(rcpS_v), d));
                myslab[lane * SLAB_P + dd] = p * rs;  // attention weight a
            }
        }
        if (PASS == 0) {
            // Column-sum the [64 rows][16 cols] slab.
            const int c = lane & 15;
            const int part = lane >> 4;
            float ps = 0.0f;
#pragma unroll
            for (int r = 0; r < 16; ++r)
                ps += myslab[(part * 16 + r) * SLAB_P + c];   // 2-way bank: free
            ps += __shfl_xor(ps, 16, 64);
            ps += __shfl_xor(ps, 32, 64);
            if ((lane >> 4) == s) mycs += ps;   // owner lane == s*16 + c == d
        } else {
            // Flush: lane stores its own row's 16 outputs (x * a), 4x float4.
            float* orow = out + ((size_t)b * T_SZ + t0 + lane) * D_SZ + s * 16;
#pragma unroll
            for (int j = 0; j < 4; ++j) {
                float4 o;
                o.x = myslab[lane * SLAB_P + 4 * j + 0] * xr[s * 4 + j].x;
                o.y = myslab[lane * SLAB_P + 4 * j + 1] * xr[s * 4 + j].y;
                o.z = myslab[lane * SLAB_P + 4 * j + 2] * xr[s * 4 + j].z;
                o.w = myslab[lane * SLAB_P + 4 * j + 3] * xr[s * 4 + j].w;
                ((float4*)orow)[j] = o;
            }
        }
    }
    if (PASS == 0) atomicAdd(&S[b * D_SZ + lane], mycs);
}

extern "C" void kernel_launch(void* const* d_in, const int* in_sizes, int n_in,
                              void* d_out, int out_size, void* d_ws, size_t ws_size,
                              hipStream_t stream) {
    const float* x = (const float*)d_in[0];
    const float* W = (const float*)d_in[1];
    const float* bias = (const float*)d_in[2];
    float* out = (float*)d_out;

    float* Wt = (float*)d_ws;                 // 4096 floats = 16 KB
    float* S = (float*)d_ws + 4096;           // B*D floats = 64 KB

    hipMemsetAsync(S, 0, B_SZ * D_SZ * sizeof(float), stream);
    tca_prep<<<1, 256, 0, stream>>>(W, Wt);

    const dim3 grid(NT * (B_SZ / WAVES));     // 32 * 64 = 2048 blocks
    const dim3 block(256);
    tca_main<0><<<grid, block, 0, stream>>>(x, Wt, bias, S, out);
    tca_main<1><<<grid, block, 0, stream>>>(x, Wt, bias, S, out);
}

// Round 4
// 179.842 us; speedup vs baseline: 2.8256x; 1.1481x over previous
//
#include <hip/hip_runtime.h>

#define B_SZ 256
#define T_SZ 2048
#define D_SZ 64
#define TILE_T 64
#define NT (T_SZ / TILE_T)           // 32 t-chunks
#define ROWS_PER_WAVE (TILE_T / 4)   // 16

__device__ __forceinline__ float fast_tanh(float s) {
    // 1 - 2/(1+exp(2s)); saturates correctly at +-inf
    return 1.0f - 2.0f * __builtin_amdgcn_rcpf(1.0f + __expf(2.0f * s));
}

// lane = output column d. Column softmax sum is lane-local (no cross-lane ops).
// PASS 0: S[b][d] += sum_rows exp(tanh(x@W + bias))
// PASS 1: out[b,t,d] = x[b,t,d] * exp(tanh(x@W + bias)) * rcp(S[b,d])
template <int PASS>
__global__ __launch_bounds__(256, 4) void tca_main(
        const float* __restrict__ x, const float* __restrict__ W,
        const float* __restrict__ bias, float* __restrict__ S,
        float* __restrict__ out) {
    __shared__ __align__(16) float xt[TILE_T * D_SZ];   // 16 KB x tile
    __shared__ __align__(16) float bt[TILE_T * D_SZ];   // 16 KB bias tile

    const int tid = threadIdx.x;
    const int wave = tid >> 6;
    const int lane = tid & 63;
    const int b = blockIdx.x & (B_SZ - 1);   // adjacent blocks share bias tile -> L2 hit
    const int tch = blockIdx.x >> 8;
    const int t0 = tch * TILE_T;

    // Stage x tile + bias tile: each is one contiguous 16 KB span, fully coalesced.
    const float4* xsrc = (const float4*)(x + ((size_t)b * T_SZ + t0) * D_SZ);
    const float4* bsrc = (const float4*)(bias + (size_t)t0 * D_SZ);
#pragma unroll
    for (int q = 0; q < 4; ++q) {
        const int i = tid + q * 256;
        ((float4*)xt)[i] = xsrc[i];
        ((float4*)bt)[i] = bsrc[i];
    }

    // W column `lane` into 64 VGPRs; coalesced dword loads, L2-hot (16 KB total).
    float Wc[D_SZ];
#pragma unroll
    for (int k = 0; k < D_SZ; ++k) Wc[k] = W[k * D_SZ + lane];

    float rcpS = 0.0f;
    if (PASS == 1) rcpS = __builtin_amdgcn_rcpf(S[b * D_SZ + lane]);
    float csum = 0.0f;

    __syncthreads();

    const int rbase = wave * ROWS_PER_WAVE;
    for (int rg = 0; rg < ROWS_PER_WAVE; rg += 4) {
        const int r0 = rbase + rg;
        float a[4][4];
#pragma unroll
        for (int j = 0; j < 4; ++j)
#pragma unroll
            for (int p = 0; p < 4; ++p) a[j][p] = 0.0f;

#pragma unroll
        for (int kk = 0; kk < 16; ++kk) {
#pragma unroll
            for (int j = 0; j < 4; ++j) {
                // wave-uniform broadcast read from LDS: conflict-free, few cycles
                const float4 xv = *(const float4*)&xt[(r0 + j) * D_SZ + kk * 4];
                a[j][0] += xv.x * Wc[4 * kk + 0];
                a[j][1] += xv.y * Wc[4 * kk + 1];
                a[j][2] += xv.z * Wc[4 * kk + 2];
                a[j][3] += xv.w * Wc[4 * kk + 3];
            }
        }
#pragma unroll
        for (int j = 0; j < 4; ++j) {
            float sv = (a[j][0] + a[j][1]) + (a[j][2] + a[j][3]);
            sv += bt[(r0 + j) * D_SZ + lane];            // per-lane, 2-way bank: free
            const float p = __expf(fast_tanh(sv));
            if (PASS == 0) {
                csum += p;                               // column sum is lane-local
            } else {
                const float xl = xt[(r0 + j) * D_SZ + lane];
                out[((size_t)b * T_SZ + t0 + r0 + j) * D_SZ + lane] = xl * p * rcpS;
            }
        }
    }
    if (PASS == 0) atomicAdd(&S[b * D_SZ + lane], csum);
}

extern "C" void kernel_launch(void* const* d_in, const int* in_sizes, int n_in,
                              void* d_out, int out_size, void* d_ws, size_t ws_size,
                              hipStream_t stream) {
    const float* x = (const float*)d_in[0];
    const float* W = (const float*)d_in[1];
    const float* bias = (const float*)d_in[2];
    float* out = (float*)d_out;
    float* S = (float*)d_ws;  // B*D floats = 64 KB

    hipMemsetAsync(S, 0, B_SZ * D_SZ * sizeof(float), stream);

    const dim3 grid(B_SZ * NT);   // 8192 blocks; bid&255 = b, bid>>8 = t-chunk
    const dim3 block(256);
    tca_main<0><<<grid, block, 0, stream>>>(x, W, bias, S, out);
    tca_main<1><<<grid, block, 0, stream>>>(x, W, bias, S, out);
}

// Round 5
// 122.480 us; speedup vs baseline: 4.1490x; 1.4683x over previous
//
#include <hip/hip_runtime.h>

typedef __attribute__((ext_vector_type(8))) short short8;   // 8 x bf16
typedef __attribute__((ext_vector_type(4))) float f32x4;
typedef __attribute__((ext_vector_type(4))) unsigned int uint4v;

#define B_SZ 256
#define T_SZ 2048
#define D_SZ 64
#define TILES_PER_WAVE 4   // 16 rows each -> 64 rows per wave
#define SEGS 8             // blocks per b; 4 waves * 64 rows * 8 = 2048 rows

__device__ __forceinline__ float fast_tanh(float s) {
    // 1 - 2/(1+exp(2s)); saturates correctly at +-inf
    return 1.0f - 2.0f * __builtin_amdgcn_rcpf(1.0f + __expf(2.0f * s));
}

// round-half-up to bf16, returned as fp32 bit pattern with low 16 bits zero
__device__ __forceinline__ unsigned int bf16_hi_bits(float f) {
    return (__float_as_uint(f) + 0x8000u) & 0xffff0000u;
}

// Pack 8 fp32 into hi/lo bf16x8 fragments: x = hi + lo (+ ~2^-15 rel residual)
__device__ __forceinline__ void pack8(const float4 a, const float4 b,
                                      short8& hi, short8& lo) {
    const float v[8] = {a.x, a.y, a.z, a.w, b.x, b.y, b.z, b.w};
    unsigned int h[4], l[4];
#pragma unroll
    for (int i = 0; i < 8; i += 2) {
        const unsigned int h0 = bf16_hi_bits(v[i]);
        const unsigned int h1 = bf16_hi_bits(v[i + 1]);
        const float l0 = v[i] - __uint_as_float(h0);
        const float l1 = v[i + 1] - __uint_as_float(h1);
        h[i >> 1] = (h0 >> 16) | (h1 & 0xffff0000u);
        l[i >> 1] = ((__float_as_uint(l0) + 0x8000u) >> 16) |
                    ((__float_as_uint(l1) + 0x8000u) & 0xffff0000u);
    }
    const uint4v hu = {h[0], h[1], h[2], h[3]};
    const uint4v lu = {l[0], l[1], l[2], l[3]};
    hi = __builtin_bit_cast(short8, hu);
    lo = __builtin_bit_cast(short8, lu);
}

// Build W fragments in MFMA B-operand order. Frag f = ((nb*2+kb)*2+h):
// lane l holds B[k = kb*32 + (l>>4)*8 + i][n = nb*16 + (l&15)], i=0..7,
// packed 2 bf16/dword, stored as 16B per lane at Wf[f*64 + l].
__global__ __launch_bounds__(256) void tca_prep(const float* __restrict__ W,
                                                unsigned int* __restrict__ Wf) {
    const int tid = threadIdx.x;
#pragma unroll
    for (int u = 0; u < 4; ++u) {
        const int lf = tid + u * 256;   // 0..1023
        const int f = lf >> 6;
        const int lane = lf & 63;
        const int nb = f >> 2;
        const int kb = (f >> 1) & 1;
        const int h = f & 1;
        const int col = nb * 16 + (lane & 15);
        const int krow = kb * 32 + (lane >> 4) * 8;
        unsigned int d[4];
#pragma unroll
        for (int i = 0; i < 8; i += 2) {
            const float w0 = W[(krow + i) * D_SZ + col];
            const float w1 = W[(krow + i + 1) * D_SZ + col];
            unsigned int b0, b1;
            if (h == 0) {
                b0 = bf16_hi_bits(w0);
                b1 = bf16_hi_bits(w1);
            } else {
                const float l0 = w0 - __uint_as_float(bf16_hi_bits(w0));
                const float l1 = w1 - __uint_as_float(bf16_hi_bits(w1));
                b0 = (__float_as_uint(l0) + 0x8000u) & 0xffff0000u;
                b1 = (__float_as_uint(l1) + 0x8000u) & 0xffff0000u;
            }
            d[i >> 1] = (b0 >> 16) | (b1 & 0xffff0000u);
        }
        const uint4v dv = {d[0], d[1], d[2], d[3]};
        ((uint4v*)Wf)[f * 64 + lane] = dv;
    }
}

// PASS 0: S[b][d] += column sums of p = exp(tanh(x@W + bias))
// PASS 1: out = x * p * rcp(S)
template <int PASS>
__global__ __launch_bounds__(256, 3) void tca_main(
        const float* __restrict__ x, const unsigned int* __restrict__ Wf,
        const float* __restrict__ bias, float* __restrict__ S,
        float* __restrict__ out) {
    const int wave = threadIdx.x >> 6;
    const int lane = threadIdx.x & 63;
    const int b = blockIdx.x >> 3;
    const int seg = blockIdx.x & (SEGS - 1);

    // W fragments resident in 64 VGPRs: wf[nb][kb][hi/lo]
    short8 wf[4][2][2];
#pragma unroll
    for (int f = 0; f < 16; ++f) {
        const uint4v v = ((const uint4v*)Wf)[f * 64 + lane];
        wf[f >> 2][(f >> 1) & 1][f & 1] = __builtin_bit_cast(short8, v);
    }

    float rcpS[4];
    if (PASS == 1) {
#pragma unroll
        for (int nb = 0; nb < 4; ++nb)
            rcpS[nb] = __builtin_amdgcn_rcpf(S[b * D_SZ + nb * 16 + (lane & 15)]);
    }
    float csum[4] = {0.f, 0.f, 0.f, 0.f};

    const int arow = lane & 15;          // A-operand row within tile
    const int acol = (lane >> 4) * 8;    // A-operand k base
    const int crow = (lane >> 4) * 4;    // C row base (+ reg)
    const int ccol = lane & 15;          // C col within 16-block

    const int t_wave = seg * 256 + wave * 64;
    for (int tile = 0; tile < TILES_PER_WAVE; ++tile) {
        const int t0 = t_wave + tile * 16;
        const float* xrow = x + ((size_t)b * T_SZ + t0 + arow) * D_SZ + acol;
        const float4 xa0 = *(const float4*)(xrow);
        const float4 xa1 = *(const float4*)(xrow + 4);
        const float4 xb0 = *(const float4*)(xrow + 32);
        const float4 xb1 = *(const float4*)(xrow + 36);

        short8 ah[2], al[2];
        pack8(xa0, xa1, ah[0], al[0]);
        pack8(xb0, xb1, ah[1], al[1]);

        f32x4 c[4];
#pragma unroll
        for (int nb = 0; nb < 4; ++nb) {
            f32x4 acc = {0.f, 0.f, 0.f, 0.f};
#pragma unroll
            for (int kb = 0; kb < 2; ++kb) {
                acc = __builtin_amdgcn_mfma_f32_16x16x32_bf16(ah[kb], wf[nb][kb][0], acc, 0, 0, 0);
                acc = __builtin_amdgcn_mfma_f32_16x16x32_bf16(ah[kb], wf[nb][kb][1], acc, 0, 0, 0);
                acc = __builtin_amdgcn_mfma_f32_16x16x32_bf16(al[kb], wf[nb][kb][0], acc, 0, 0, 0);
            }
            c[nb] = acc;
        }

#pragma unroll
        for (int nb = 0; nb < 4; ++nb) {
#pragma unroll
            for (int r = 0; r < 4; ++r) {
                const int t = t0 + crow + r;
                const int d = nb * 16 + ccol;
                const size_t gi = ((size_t)b * T_SZ + t) * D_SZ + d;
                const float e = c[nb][r] + bias[(size_t)t * D_SZ + d];
                const float p = __expf(fast_tanh(e));
                if (PASS == 0) {
                    csum[nb] += p;
                } else {
                    out[gi] = x[gi] * p * rcpS[nb];
                }
            }
        }
    }

    if (PASS == 0) {
#pragma unroll
        for (int nb = 0; nb < 4; ++nb) {
            float v = csum[nb];
            v += __shfl_xor(v, 16, 64);
            v += __shfl_xor(v, 32, 64);
            if (lane < 16) atomicAdd(&S[b * D_SZ + nb * 16 + lane], v);
        }
    }
}

extern "C" void kernel_launch(void* const* d_in, const int* in_sizes, int n_in,
                              void* d_out, int out_size, void* d_ws, size_t ws_size,
                              hipStream_t stream) {
    const float* x = (const float*)d_in[0];
    const float* W = (const float*)d_in[1];
    const float* bias = (const float*)d_in[2];
    float* out = (float*)d_out;

    unsigned int* Wf = (unsigned int*)d_ws;   // 16 KB of W fragments
    float* S = (float*)d_ws + 4096;           // B*D floats = 64 KB

    hipMemsetAsync(S, 0, B_SZ * D_SZ * sizeof(float), stream);
    tca_prep<<<1, 256, 0, stream>>>(W, Wf);

    const dim3 grid(B_SZ * SEGS);   // 2048 blocks, 4 waves each
    const dim3 block(256);
    tca_main<0><<<grid, block, 0, stream>>>(x, Wf, bias, S, out);
    tca_main<1><<<grid, block, 0, stream>>>(x, Wf, bias, S, out);
}

// Round 7
// 102.952 us; speedup vs baseline: 4.9360x; 1.1897x over previous
//
#include <hip/hip_runtime.h>

typedef __attribute__((ext_vector_type(8))) short short8;   // 8 x bf16
typedef __attribute__((ext_vector_type(4))) float f32x4;
typedef __attribute__((ext_vector_type(4))) unsigned int uint4v;

#define B_SZ 256
#define T_SZ 2048
#define D_SZ 64
#define TILES_PER_WAVE 4   // 16 rows each -> 64 rows per wave
#define SEGS 8             // blocks per b; 4 waves * 64 rows * 8 = 2048 rows
#define APAD 68            // a_lds row stride in dwords (68%32=4 -> 2-way writes)

#define KEEP(v) asm volatile("" : "+v"(v))

// round-half-up to bf16, returned as fp32 bit pattern with low 16 bits zero
__device__ __forceinline__ unsigned int bf16_hi_bits(float f) {
    return (__float_as_uint(f) + 0x8000u) & 0xffff0000u;
}

// Split 8 fp32 into hi (+ optional lo) bf16x8 MFMA A-fragments: x = hi + lo
template <bool LO>
__device__ __forceinline__ void split8(const float4 a, const float4 b,
                                       short8& hi, short8& lo) {
    const float v[8] = {a.x, a.y, a.z, a.w, b.x, b.y, b.z, b.w};
    unsigned int h[4], l[4];
#pragma unroll
    for (int i = 0; i < 8; i += 2) {
        const unsigned int h0 = bf16_hi_bits(v[i]);
        const unsigned int h1 = bf16_hi_bits(v[i + 1]);
        h[i >> 1] = (h0 >> 16) | (h1 & 0xffff0000u);
        if (LO) {
            const float l0 = v[i] - __uint_as_float(h0);
            const float l1 = v[i + 1] - __uint_as_float(h1);
            l[i >> 1] = ((__float_as_uint(l0) + 0x8000u) >> 16) |
                        ((__float_as_uint(l1) + 0x8000u) & 0xffff0000u);
        }
    }
    const uint4v hu = {h[0], h[1], h[2], h[3]};
    hi = __builtin_bit_cast(short8, hu);
    if (LO) {
        const uint4v lu = {l[0], l[1], l[2], l[3]};
        lo = __builtin_bit_cast(short8, lu);
    }
}

// Build W fragments in MFMA B-operand order. Frag f = ((nb*2+kb)*2+h):
// lane l holds B[k = kb*32 + (l>>4)*8 + i][n = nb*16 + (l&15)], i=0..7.
__global__ __launch_bounds__(256) void tca_prep(const float* __restrict__ W,
                                                unsigned int* __restrict__ Wf) {
    const int tid = threadIdx.x;
#pragma unroll
    for (int u = 0; u < 4; ++u) {
        const int lf = tid + u * 256;   // 0..1023
        const int f = lf >> 6;
        const int lane = lf & 63;
        const int nb = f >> 2;
        const int kb = (f >> 1) & 1;
        const int h = f & 1;
        const int col = nb * 16 + (lane & 15);
        const int krow = kb * 32 + (lane >> 4) * 8;
        unsigned int d[4];
#pragma unroll
        for (int i = 0; i < 8; i += 2) {
            const float w0 = W[(krow + i) * D_SZ + col];
            const float w1 = W[(krow + i + 1) * D_SZ + col];
            unsigned int b0, b1;
            if (h == 0) {
                b0 = bf16_hi_bits(w0);
                b1 = bf16_hi_bits(w1);
            } else {
                const float l0 = w0 - __uint_as_float(bf16_hi_bits(w0));
                const float l1 = w1 - __uint_as_float(bf16_hi_bits(w1));
                b0 = (__float_as_uint(l0) + 0x8000u) & 0xffff0000u;
                b1 = (__float_as_uint(l1) + 0x8000u) & 0xffff0000u;
            }
            d[i >> 1] = (b0 >> 16) | (b1 & 0xffff0000u);
        }
        const uint4v dv = {d[0], d[1], d[2], d[3]};
        ((uint4v*)Wf)[f * 64 + lane] = dv;
    }
}

// PASS 0: S[b][d] += column sums of p = exp(tanh(x@W + bias))  [bf16-hi matmul]
// PASS 1: out = x * p * rcp(S)                                 [3-term split matmul]
template <int PASS>
__global__ __launch_bounds__(256, 2) void tca_main(
        const float* __restrict__ x, const unsigned int* __restrict__ Wf,
        const float* __restrict__ bias, float* __restrict__ S,
        float* __restrict__ out) {
    __shared__ float a_lds[4][16 * APAD];   // per-wave a-transpose slab (PASS1)

    const int wave = threadIdx.x >> 6;
    const int lane = threadIdx.x & 63;
    const int b = blockIdx.x >> 3;
    const int seg = blockIdx.x & (SEGS - 1);

    const int arow = lane & 15;          // A row within 16-row tile
    const int aoff = (lane >> 4) * 8;    // A k-base within 32-block
    const int crow = (lane >> 4) * 4;    // C row base
    const int ccol = lane & 15;          // C col within 16-block

    // W fragments -> registers, pinned with empty-asm keeps.
    short8 wh[4][2], wl[4][2];
#pragma unroll
    for (int nb = 0; nb < 4; ++nb)
#pragma unroll
        for (int kb = 0; kb < 2; ++kb) {
            const int fb = (nb * 2 + kb) * 2;
            wh[nb][kb] = __builtin_bit_cast(short8, ((const uint4v*)Wf)[fb * 64 + lane]);
            KEEP(wh[nb][kb]);
            if (PASS == 1) {
                wl[nb][kb] = __builtin_bit_cast(short8, ((const uint4v*)Wf)[(fb + 1) * 64 + lane]);
                KEEP(wl[nb][kb]);
            }
        }

    float rcpS[4];
    if (PASS == 1) {
#pragma unroll
        for (int nb = 0; nb < 4; ++nb)
            rcpS[nb] = __builtin_amdgcn_rcpf(S[b * D_SZ + nb * 16 + ccol]);
    }
    float csum[4] = {0.f, 0.f, 0.f, 0.f};

    const int t_wave = seg * 256 + wave * 64;
    for (int tile = 0; tile < TILES_PER_WAVE; ++tile) {
        const int t0 = t_wave + tile * 16;
        const float* xrow = x + ((size_t)b * T_SZ + t0 + arow) * D_SZ + aoff;
        const float4 xa0 = *(const float4*)(xrow);
        const float4 xa1 = *(const float4*)(xrow + 4);
        const float4 xb0 = *(const float4*)(xrow + 32);
        const float4 xb1 = *(const float4*)(xrow + 36);

        short8 ah[2], al[2];
        if (PASS == 0) {
            split8<false>(xa0, xa1, ah[0], al[0]);
            split8<false>(xb0, xb1, ah[1], al[1]);
        } else {
            split8<true>(xa0, xa1, ah[0], al[0]);
            split8<true>(xb0, xb1, ah[1], al[1]);
        }

        f32x4 c[4];
#pragma unroll
        for (int nb = 0; nb < 4; ++nb) {
            f32x4 acc = {0.f, 0.f, 0.f, 0.f};
#pragma unroll
            for (int kb = 0; kb < 2; ++kb) {
                acc = __builtin_amdgcn_mfma_f32_16x16x32_bf16(ah[kb], wh[nb][kb], acc, 0, 0, 0);
                if (PASS == 1) {
                    acc = __builtin_amdgcn_mfma_f32_16x16x32_bf16(ah[kb], wl[nb][kb], acc, 0, 0, 0);
                    acc = __builtin_amdgcn_mfma_f32_16x16x32_bf16(al[kb], wh[nb][kb], acc, 0, 0, 0);
                }
            }
            c[nb] = acc;
        }

        // Epilogue at C-layout; bias via L2-hot scattered dwords off one base.
        const float* brow = bias + (size_t)(t0 + crow) * D_SZ + ccol;
#pragma unroll
        for (int nb = 0; nb < 4; ++nb) {
#pragma unroll
            for (int r = 0; r < 4; ++r) {
                const float e = c[nb][r] + brow[r * D_SZ + nb * 16];
                const float u = __expf(2.0f * e);
                const float rr = __builtin_amdgcn_rcpf(1.0f + u);
                const float p = __expf(1.0f - 2.0f * rr);   // exp(tanh(e))
                if (PASS == 0) {
                    csum[nb] += p;
                } else {
                    a_lds[wave][(crow + r) * APAD + nb * 16 + ccol] = p * rcpS[nb];
                }
            }
        }

        if (PASS == 1) {
            // Read a back at A-layout (wave-private: compiler orders via lgkmcnt),
            // multiply with register-resident x, store coalesced float4s.
            const float* as = &a_lds[wave][arow * APAD + aoff];
            const float4 a0 = *(const float4*)(as);
            const float4 a1 = *(const float4*)(as + 4);
            const float4 a2 = *(const float4*)(as + 32);
            const float4 a3 = *(const float4*)(as + 36);
            float* orow = out + ((size_t)b * T_SZ + t0 + arow) * D_SZ + aoff;
            float4 o;
            o.x = xa0.x * a0.x; o.y = xa0.y * a0.y; o.z = xa0.z * a0.z; o.w = xa0.w * a0.w;
            *(float4*)(orow) = o;
            o.x = xa1.x * a1.x; o.y = xa1.y * a1.y; o.z = xa1.z * a1.z; o.w = xa1.w * a1.w;
            *(float4*)(orow + 4) = o;
            o.x = xb0.x * a2.x; o.y = xb0.y * a2.y; o.z = xb0.z * a2.z; o.w = xb0.w * a2.w;
            *(float4*)(orow + 32) = o;
            o.x = xb1.x * a3.x; o.y = xb1.y * a3.y; o.z = xb1.z * a3.z; o.w = xb1.w * a3.w;
            *(float4*)(orow + 36) = o;
        }
    }

    if (PASS == 0) {
#pragma unroll
        for (int nb = 0; nb < 4; ++nb) {
            float v = csum[nb];
            v += __shfl_xor(v, 16, 64);
            v += __shfl_xor(v, 32, 64);
            if (lane < 16) atomicAdd(&S[b * D_SZ + nb * 16 + lane], v);
        }
    }
}

extern "C" void kernel_launch(void* const* d_in, const int* in_sizes, int n_in,
                              void* d_out, int out_size, void* d_ws, size_t ws_size,
                              hipStream_t stream) {
    const float* x = (const float*)d_in[0];
    const float* W = (const float*)d_in[1];
    const float* bias = (const float*)d_in[2];
    float* out = (float*)d_out;

    unsigned int* Wf = (unsigned int*)d_ws;   // 16 KB of W fragments
    float* S = (float*)d_ws + 4096;           // B*D floats = 64 KB

    (void)hipMemsetAsync(S, 0, B_SZ * D_SZ * sizeof(float), stream);
    tca_prep<<<1, 256, 0, stream>>>(W, Wf);

    const dim3 grid(B_SZ * SEGS);   // 2048 blocks, 4 waves each
    const dim3 block(256);
    tca_main<0><<<grid, block, 0, stream>>>(x, Wf, bias, S, out);
    tca_main<1><<<grid, block, 0, stream>>>(x, Wf, bias, S, out);
}

// Round 8
// 99.003 us; speedup vs baseline: 5.1328x; 1.0399x over previous
//
#include <hip/hip_runtime.h>

typedef __attribute__((ext_vector_type(8))) short short8;   // 8 x bf16
typedef __attribute__((ext_vector_type(4))) float f32x4;
typedef __attribute__((ext_vector_type(4))) unsigned int uint4v;

#define B_SZ 256
#define T_SZ 2048
#define D_SZ 64
#define TILES_PER_WAVE 4   // 16 rows each -> 64 rows per wave
#define SEGS 8             // blocks per b; 4 waves * 64 rows * 8 = 2048 rows
#define APAD 68            // a_lds row stride in dwords (68%32=4 -> 2-way writes)

#define KEEP(v) asm volatile("" : "+v"(v))

// round-half-up to bf16, returned as fp32 bit pattern with low 16 bits zero
__device__ __forceinline__ unsigned int bf16_hi_bits(float f) {
    return (__float_as_uint(f) + 0x8000u) & 0xffff0000u;
}

// Split 8 fp32 into hi (+ optional lo) bf16x8 MFMA A-fragments: x = hi + lo
template <bool LO>
__device__ __forceinline__ void split8(const float4 a, const float4 b,
                                       short8& hi, short8& lo) {
    const float v[8] = {a.x, a.y, a.z, a.w, b.x, b.y, b.z, b.w};
    unsigned int h[4], l[4];
#pragma unroll
    for (int i = 0; i < 8; i += 2) {
        const unsigned int h0 = bf16_hi_bits(v[i]);
        const unsigned int h1 = bf16_hi_bits(v[i + 1]);
        h[i >> 1] = (h0 >> 16) | (h1 & 0xffff0000u);
        if (LO) {
            const float l0 = v[i] - __uint_as_float(h0);
            const float l1 = v[i + 1] - __uint_as_float(h1);
            l[i >> 1] = ((__float_as_uint(l0) + 0x8000u) >> 16) |
                        ((__float_as_uint(l1) + 0x8000u) & 0xffff0000u);
        }
    }
    const uint4v hu = {h[0], h[1], h[2], h[3]};
    hi = __builtin_bit_cast(short8, hu);
    if (LO) {
        const uint4v lu = {l[0], l[1], l[2], l[3]};
        lo = __builtin_bit_cast(short8, lu);
    }
}

// Grid of 16 blocks: every block zeroes its 4 KB slice of S; block 0 also
// builds W fragments in MFMA B-operand order. Frag f = ((nb*2+kb)*2+h):
// lane l holds B[k = kb*32 + (l>>4)*8 + i][n = nb*16 + (l&15)], i=0..7.
__global__ __launch_bounds__(256) void tca_prep(const float* __restrict__ W,
                                                unsigned int* __restrict__ Wf,
                                                float* __restrict__ S) {
    const int tid = threadIdx.x;
    const float4 z = make_float4(0.f, 0.f, 0.f, 0.f);
    ((float4*)S)[blockIdx.x * 256 + tid] = z;   // 16 blocks * 4 KB = 64 KB

    if (blockIdx.x != 0) return;
#pragma unroll
    for (int u = 0; u < 4; ++u) {
        const int lf = tid + u * 256;   // 0..1023
        const int f = lf >> 6;
        const int lane = lf & 63;
        const int nb = f >> 2;
        const int kb = (f >> 1) & 1;
        const int h = f & 1;
        const int col = nb * 16 + (lane & 15);
        const int krow = kb * 32 + (lane >> 4) * 8;
        unsigned int d[4];
#pragma unroll
        for (int i = 0; i < 8; i += 2) {
            const float w0 = W[(krow + i) * D_SZ + col];
            const float w1 = W[(krow + i + 1) * D_SZ + col];
            unsigned int b0, b1;
            if (h == 0) {
                b0 = bf16_hi_bits(w0);
                b1 = bf16_hi_bits(w1);
            } else {
                const float l0 = w0 - __uint_as_float(bf16_hi_bits(w0));
                const float l1 = w1 - __uint_as_float(bf16_hi_bits(w1));
                b0 = (__float_as_uint(l0) + 0x8000u) & 0xffff0000u;
                b1 = (__float_as_uint(l1) + 0x8000u) & 0xffff0000u;
            }
            d[i >> 1] = (b0 >> 16) | (b1 & 0xffff0000u);
        }
        const uint4v dv = {d[0], d[1], d[2], d[3]};
        ((uint4v*)Wf)[f * 64 + lane] = dv;
    }
}

// PASS 0: S[b][d] += column sums of p = exp(tanh(x@W + bias))  [bf16-hi matmul]
// PASS 1: out = x * p * rcp(S)                                 [3-term split matmul]
template <int PASS>
__global__ __launch_bounds__(256, 2) void tca_main(
        const float* __restrict__ x, const unsigned int* __restrict__ Wf,
        const float* __restrict__ bias, float* __restrict__ S,
        float* __restrict__ out) {
    __shared__ float a_lds[4][16 * APAD];   // per-wave a-transpose slab (PASS1)

    const int wave = threadIdx.x >> 6;
    const int lane = threadIdx.x & 63;
    const int b = blockIdx.x >> 3;
    const int seg = blockIdx.x & (SEGS - 1);

    const int arow = lane & 15;          // A row within 16-row tile
    const int aoff = (lane >> 4) * 8;    // A k-base within 32-block
    const int crow = (lane >> 4) * 4;    // C row base
    const int ccol = lane & 15;          // C col within 16-block

    // W fragments -> registers, pinned with empty-asm keeps.
    short8 wh[4][2], wl[4][2];
#pragma unroll
    for (int nb = 0; nb < 4; ++nb)
#pragma unroll
        for (int kb = 0; kb < 2; ++kb) {
            const int fb = (nb * 2 + kb) * 2;
            wh[nb][kb] = __builtin_bit_cast(short8, ((const uint4v*)Wf)[fb * 64 + lane]);
            KEEP(wh[nb][kb]);
            if (PASS == 1) {
                wl[nb][kb] = __builtin_bit_cast(short8, ((const uint4v*)Wf)[(fb + 1) * 64 + lane]);
                KEEP(wl[nb][kb]);
            }
        }

    float rcpS[4];
    if (PASS == 1) {
#pragma unroll
        for (int nb = 0; nb < 4; ++nb)
            rcpS[nb] = __builtin_amdgcn_rcpf(S[b * D_SZ + nb * 16 + ccol]);
    }
    float csum[4] = {0.f, 0.f, 0.f, 0.f};

    const int t_wave = seg * 256 + wave * 64;
    for (int tile = 0; tile < TILES_PER_WAVE; ++tile) {
        const int t0 = t_wave + tile * 16;
        const float* xrow = x + ((size_t)b * T_SZ + t0 + arow) * D_SZ + aoff;
        const float4 xa0 = *(const float4*)(xrow);
        const float4 xa1 = *(const float4*)(xrow + 4);
        const float4 xb0 = *(const float4*)(xrow + 32);
        const float4 xb1 = *(const float4*)(xrow + 36);

        short8 ah[2], al[2];
        if (PASS == 0) {
            split8<false>(xa0, xa1, ah[0], al[0]);
            split8<false>(xb0, xb1, ah[1], al[1]);
        } else {
            split8<true>(xa0, xa1, ah[0], al[0]);
            split8<true>(xb0, xb1, ah[1], al[1]);
        }

        f32x4 c[4];
#pragma unroll
        for (int nb = 0; nb < 4; ++nb) {
            f32x4 acc = {0.f, 0.f, 0.f, 0.f};
#pragma unroll
            for (int kb = 0; kb < 2; ++kb) {
                acc = __builtin_amdgcn_mfma_f32_16x16x32_bf16(ah[kb], wh[nb][kb], acc, 0, 0, 0);
                if (PASS == 1) {
                    acc = __builtin_amdgcn_mfma_f32_16x16x32_bf16(ah[kb], wl[nb][kb], acc, 0, 0, 0);
                    acc = __builtin_amdgcn_mfma_f32_16x16x32_bf16(al[kb], wh[nb][kb], acc, 0, 0, 0);
                }
            }
            c[nb] = acc;
        }

        // Epilogue at C-layout; bias via L2-hot scattered dwords off one base.
        const float* brow = bias + (size_t)(t0 + crow) * D_SZ + ccol;
#pragma unroll
        for (int nb = 0; nb < 4; ++nb) {
#pragma unroll
            for (int r = 0; r < 4; ++r) {
                const float e = c[nb][r] + brow[r * D_SZ + nb * 16];
                const float u = __expf(2.0f * e);
                const float rr = __builtin_amdgcn_rcpf(1.0f + u);
                const float p = __expf(1.0f - 2.0f * rr);   // exp(tanh(e))
                if (PASS == 0) {
                    csum[nb] += p;
                } else {
                    a_lds[wave][(crow + r) * APAD + nb * 16 + ccol] = p * rcpS[nb];
                }
            }
        }

        if (PASS == 1) {
            // Read a back at A-layout (wave-private: compiler orders via lgkmcnt),
            // multiply with register-resident x, store coalesced float4s.
            const float* as = &a_lds[wave][arow * APAD + aoff];
            const float4 a0 = *(const float4*)(as);
            const float4 a1 = *(const float4*)(as + 4);
            const float4 a2 = *(const float4*)(as + 32);
            const float4 a3 = *(const float4*)(as + 36);
            float* orow = out + ((size_t)b * T_SZ + t0 + arow) * D_SZ + aoff;
            float4 o;
            o.x = xa0.x * a0.x; o.y = xa0.y * a0.y; o.z = xa0.z * a0.z; o.w = xa0.w * a0.w;
            *(float4*)(orow) = o;
            o.x = xa1.x * a1.x; o.y = xa1.y * a1.y; o.z = xa1.z * a1.z; o.w = xa1.w * a1.w;
            *(float4*)(orow + 4) = o;
            o.x = xb0.x * a2.x; o.y = xb0.y * a2.y; o.z = xb0.z * a2.z; o.w = xb0.w * a2.w;
            *(float4*)(orow + 32) = o;
            o.x = xb1.x * a3.x; o.y = xb1.y * a3.y; o.z = xb1.z * a3.z; o.w = xb1.w * a3.w;
            *(float4*)(orow + 36) = o;
        }
    }

    if (PASS == 0) {
#pragma unroll
        for (int nb = 0; nb < 4; ++nb) {
            float v = csum[nb];
            v += __shfl_xor(v, 16, 64);
            v += __shfl_xor(v, 32, 64);
            if (lane < 16) atomicAdd(&S[b * D_SZ + nb * 16 + lane], v);
        }
    }
}

extern "C" void kernel_launch(void* const* d_in, const int* in_sizes, int n_in,
                              void* d_out, int out_size, void* d_ws, size_t ws_size,
                              hipStream_t stream) {
    const float* x = (const float*)d_in[0];
    const float* W = (const float*)d_in[1];
    const float* bias = (const float*)d_in[2];
    float* out = (float*)d_out;

    unsigned int* Wf = (unsigned int*)d_ws;   // 16 KB of W fragments
    float* S = (float*)d_ws + 4096;           // B*D floats = 64 KB

    tca_prep<<<16, 256, 0, stream>>>(W, Wf, S);   // zeroes S + builds Wf

    const dim3 grid(B_SZ * SEGS);   // 2048 blocks, 4 waves each
    const dim3 block(256);
    tca_main<0><<<grid, block, 0, stream>>>(x, Wf, bias, S, out);
    tca_main<1><<<grid, block, 0, stream>>>(x, Wf, bias, S, out);
}